// Round 12
// baseline (291.252 us; speedup 1.0000x reference)
//
#include <hip/hip_runtime.h>
#include <cstdint>

// FCOS detection post-process for MI355X.
// Pipeline: score/box decode -> per-image exact top-1000 (bitonic chunk sort +
// tree merge) -> suppression bitmask -> LDS-staged greedy NMS scan -> outputs.
// THIS ROUND: +2 ablation probes for the nms_scan 45us wall (R7-R11 all
// pinned at 45us across 5 structures; models say <15us -> ablate, don't guess).

typedef unsigned long long ull;

#define BATCH 16
#define NLOC 17064      // total FPN locations per image
#define NPAD 18432      // padded to 9 * 2048
#define NCHUNK 9
#define CHUNK 2048
#define TOPK 1000
#define TOPKP 1024
#define NCLS 80
#define SCORE_THR 0.05f
#define IOU_THR 0.6f

struct Ptrs { const float* cls[5]; const float* reg[5]; const float* ctr[5]; };

// ---------------------------------------------------------------- kernel 1 --
__global__ __launch_bounds__(256) void score_kernel(Ptrs p, ull* __restrict__ keys,
                                                    int* __restrict__ labels,
                                                    float* __restrict__ boxes) {
  int idx = blockIdx.x * 256 + threadIdx.x;
  if (idx >= BATCH * NPAD) return;
  int b = idx / NPAD, n = idx - b * NPAD;
  if (n >= NLOC) { keys[idx] = 0ull; return; }

  int lvl, off, lw, st, H;
  if (n < 12800)      { lvl=0; off=0;     lw=7; st=8;   H=100; }
  else if (n < 16000) { lvl=1; off=12800; lw=6; st=16;  H=50;  }
  else if (n < 16800) { lvl=2; off=16000; lw=5; st=32;  H=25;  }
  else if (n < 17008) { lvl=3; off=16800; lw=4; st=64;  H=13;  }
  else                { lvl=4; off=17008; lw=3; st=128; H=7;   }
  int hw = n - off;
  int w = hw & ((1 << lw) - 1), h = hw >> lw;
  int HW = H << lw;
  float fs = (float)st, half = fs * 0.5f;
  float x = (float)w * fs + half, y = (float)h * fs + half;

  const float* cb = p.cls[lvl] + (size_t)b * NCLS * HW + hw;
  float best = cb[0]; int bi = 0;
  for (int c = 1; c < NCLS; ++c) {
    float v = cb[(size_t)c * HW];
    if (v > best) { best = v; bi = c; }   // strict > keeps first max (jnp.argmax)
  }
  const float* rb = p.reg[lvl] + (size_t)b * 4 * HW + hw;
  float r0 = rb[0], r1 = rb[HW], r2 = rb[2 * (size_t)HW], r3 = rb[3 * (size_t)HW];
  float ct = p.ctr[lvl][(size_t)b * HW + hw];

  float pcls = 1.f / (1.f + expf(-best));
  float pctr = 1.f / (1.f + expf(-ct));
  float score = sqrtf(pcls * pctr);

  keys[idx] = ((ull)__float_as_uint(score) << 32) | (ull)(0xFFFFFFFFu - (unsigned)n);
  labels[(size_t)b * NLOC + n] = bi + 1;
  float* bx = boxes + ((size_t)b * NLOC + n) * 4;
  bx[0] = x - r0; bx[1] = y - r1; bx[2] = x + r2; bx[3] = y + r3;
}

// ---------------------------------------------------------------- kernel 2 --
__global__ __launch_bounds__(512) void chunk_sort_kernel(const ull* __restrict__ keys,
                                                         ull* __restrict__ runs) {
  __shared__ ull s[CHUNK];
  int b = blockIdx.x / NCHUNK, c = blockIdx.x % NCHUNK;
  const ull* src = keys + (size_t)b * NPAD + (size_t)c * CHUNK;
  for (int i = threadIdx.x; i < CHUNK; i += 512) s[i] = src[i];
  __syncthreads();
  for (int k = 2; k <= CHUNK; k <<= 1) {
    for (int j = k >> 1; j > 0; j >>= 1) {
      for (int t = threadIdx.x; t < CHUNK / 2; t += 512) {
        int i = ((t & ~(j - 1)) << 1) | (t & (j - 1));
        int ixj = i | j;
        bool desc = (i & k) == 0;
        ull a = s[i], bb = s[ixj];
        bool sw = desc ? (a < bb) : (a > bb);
        if (sw) { s[i] = bb; s[ixj] = a; }
      }
      __syncthreads();
    }
  }
  ull* dst = runs + ((size_t)b * NCHUNK + c) * TOPKP;
  for (int i = threadIdx.x; i < TOPKP; i += 512) dst[i] = s[i];
}

// ---------------------------------------------------------------- kernel 3 --
__global__ __launch_bounds__(512) void merge_level_kernel(const ull* __restrict__ src,
    ull* __restrict__ dst, int npairs, int carry, int srcRPI, int dstRPI) {
  int per = npairs + carry;
  int b = blockIdx.x / per, p = blockIdx.x % per;
  const ull* sb = src + (size_t)b * srcRPI * TOPKP;
  ull* db = dst + (size_t)b * dstRPI * TOPKP;
  int tid = threadIdx.x;
  if (p >= npairs) {   // carry: copy last odd run through
    for (int i = tid; i < TOPKP; i += 512)
      db[(size_t)p * TOPKP + i] = sb[(size_t)(2 * npairs) * TOPKP + i];
    return;
  }
  __shared__ ull m[TOPKP];
  const ull* A = sb + (size_t)(2 * p) * TOPKP;
  const ull* B = sb + (size_t)(2 * p + 1) * TOPKP;
  for (int i = tid; i < TOPKP; i += 512) {
    ull a = A[i], c = B[TOPKP - 1 - i];
    m[i] = a > c ? a : c;
  }
  __syncthreads();
  for (int j = TOPKP / 2; j > 0; j >>= 1) {
    for (int t = tid; t < TOPKP / 2; t += 512) {
      int i = ((t & ~(j - 1)) << 1) | (t & (j - 1));
      int ixj = i | j;
      ull a = m[i], c = m[ixj];
      if (a < c) { m[i] = c; m[ixj] = a; }
    }
    __syncthreads();
  }
  for (int i = tid; i < TOPKP; i += 512) db[(size_t)p * TOPKP + i] = m[i];
}

// ---------------------------------------------------------------- kernel 4 --
__global__ __launch_bounds__(256) void gather_kernel(const ull* __restrict__ topkeys,
    const int* __restrict__ labels, const float* __restrict__ boxes,
    float* __restrict__ topS, int* __restrict__ topL, float* __restrict__ topOB,
    ull* __restrict__ validWords, float* __restrict__ outBoxes) {
  __shared__ float red[256];
  __shared__ float s_cmax;
  int b = blockIdx.x, tid = threadIdx.x;
  float lmax = 0.f;
  for (int k = tid; k < TOPKP; k += 256) {
    ull key = topkeys[(size_t)b * TOPKP + k];
    float sc = 0.f; int lb = 0;
    float b0 = 0.f, b1 = 0.f, b2 = 0.f, b3 = 0.f;
    bool inR = (k < TOPK);
    if (inR) {
      sc = __uint_as_float((unsigned)(key >> 32));
      unsigned n = 0xFFFFFFFFu - (unsigned)(key & 0xFFFFFFFFull);
      lb = labels[(size_t)b * NLOC + n];
      const float* bp = boxes + ((size_t)b * NLOC + n) * 4;
      b0 = bp[0]; b1 = bp[1]; b2 = bp[2]; b3 = bp[3];
      float* ob = outBoxes + ((size_t)b * TOPK + k) * 4;
      ob[0] = b0; ob[1] = b1; ob[2] = b2; ob[3] = b3;
    }
    topS[(size_t)b * TOPKP + k] = sc;
    topL[(size_t)b * TOPKP + k] = lb;
    float* tb = topOB + ((size_t)b * TOPKP + k) * 4;
    tb[0] = b0; tb[1] = b1; tb[2] = b2; tb[3] = b3;
    bool valid = inR && (sc > SCORE_THR);
    if (valid) lmax = fmaxf(lmax, fmaxf(fmaxf(b0, b1), fmaxf(b2, b3)));
    ull vb = __ballot(valid ? 1 : 0);
    if ((tid & 63) == 0) validWords[b * 16 + (k >> 6)] = vb;
  }
  red[tid] = lmax;
  __syncthreads();
  for (int sft = 128; sft > 0; sft >>= 1) {
    if (tid < sft) red[tid] = fmaxf(red[tid], red[tid + sft]);
    __syncthreads();
  }
  if (tid == 0) s_cmax = red[0];
  __syncthreads();
  float offb = s_cmax + 1.0f;
  for (int k = tid; k < TOPKP; k += 256) {
    float off = (float)topL[(size_t)b * TOPKP + k] * offb;
    float* tb = topOB + ((size_t)b * TOPKP + k) * 4;
    tb[0] += off; tb[1] += off; tb[2] += off; tb[3] += off;
  }
}

// ---------------------------------------------------------------- kernel 5 --
__global__ __launch_bounds__(1024) void sup_kernel(const float* __restrict__ topOB,
                                                   ull* __restrict__ sup) {
  int bid = blockIdx.x;
  int b = bid / TOPK, i = bid - b * TOPK;
  int j = threadIdx.x;
  const float4* OB = (const float4*)topOB + (size_t)b * TOPKP;
  float4 A = OB[i];
  float aw = fmaxf(A.z - A.x, 0.f), ah = fmaxf(A.w - A.y, 0.f);
  float areaA = aw * ah;
  bool bit = false;
  if (j > i && j < TOPK) {
    float4 Bx = OB[j];
    float bw = fmaxf(Bx.z - Bx.x, 0.f), bh = fmaxf(Bx.w - Bx.y, 0.f);
    float areaB = bw * bh;
    float ix1 = fmaxf(A.x, Bx.x), iy1 = fmaxf(A.y, Bx.y);
    float ix2 = fminf(A.z, Bx.z), iy2 = fminf(A.w, Bx.w);
    float inter = fmaxf(ix2 - ix1, 0.f) * fmaxf(iy2 - iy1, 0.f);
    float uni = areaA + areaB - inter;
    float iou = inter / fmaxf(uni, 1e-9f);
    bit = iou > IOU_THR;
  }
  ull m = __ballot(bit ? 1 : 0);
  if ((j & 63) == 0) sup[((size_t)b * TOPKP + i) * 16 + (j >> 6)] = m;
}

// ------------------------------------------------------------ probe A ------
// Pure memory path of nms_scan: identical 8-group x 8-load/thread reg-batched
// pattern over the same sup addresses, XOR checksum -> ws scratch. If this is
// ~40us the wall is the load path; if ~5us the loads were never the wall.
__global__ __launch_bounds__(256) void nms_probe_load(const ull* __restrict__ sup,
                                                      ull* __restrict__ scratch) {
  int b = blockIdx.x, tid = threadIdx.x;
  const ull* S = sup + (size_t)b * TOPKP * 16;
  ull acc = 0;
  for (int g = 0; g < 8; ++g) {
    const ull* src = S + (size_t)g * 2048;
    ull s0 = src[tid],        s1 = src[tid + 256],  s2 = src[tid + 512],
        s3 = src[tid + 768],  s4 = src[tid + 1024], s5 = src[tid + 1280],
        s6 = src[tid + 1536], s7 = src[tid + 1792];
    acc ^= s0 ^ s1 ^ s2 ^ s3 ^ s4 ^ s5 ^ s6 ^ s7;
    __syncthreads();
  }
  scratch[(size_t)b * 256 + tid] = acc;
}

// ------------------------------------------------------------ probe B ------
// Pure compute/LDS path of nms_scan: stage ONE 16KB group, then run the full
// 8-group x 2-span chain + phase B against it (identical instruction mix,
// zero global loads in the loop). If ~40us the wall is the chain/LDS path.
#define CS(K) { unsigned rl = __builtin_amdgcn_readlane(dlo, (K));             \
    unsigned rh = __builtin_amdgcn_readlane(dhi, (K));                         \
    ull take = (M >> (K)) & 1ull; ull msk = 0ull - take;                       \
    M &= ~((((ull)rh << 32) | (ull)rl) & msk); km |= take << (K); }
#define CS8(B8) CS((B8)+0) CS((B8)+1) CS((B8)+2) CS((B8)+3) CS((B8)+4)         \
    CS((B8)+5) CS((B8)+6) CS((B8)+7)

__global__ __launch_bounds__(256) void nms_probe_chain(const ull* __restrict__ sup,
    const ull* __restrict__ validWords, ull* __restrict__ scratch) {
  __shared__ ull ls[2048];
  int b = blockIdx.x, tid = threadIdx.x;
  int wave = tid >> 6, lane = tid & 63;
  const ull* S = sup + (size_t)b * TOPKP * 16;
  for (int k = tid; k < 2048; k += 256) ls[k] = S[k];
  ull rm = 0xFFFFFFFFFFFFFFFFull;
  if (wave == 0 && lane < 16) rm = ~validWords[b * 16 + lane];
  __syncthreads();
  for (int g = 0; g < 8; ++g) {
    if (wave == 0) {
      int lg = lane >> 4, wd = lane & 15;
      for (int wl = 0; wl < 2; ++wl) {
        int w = 2 * g + wl;
        ull dg = ls[(size_t)(wl * 64 + lane) * 16 + w];
        unsigned dlo = (unsigned)dg, dhi = (unsigned)(dg >> 32);
        unsigned mlo = __builtin_amdgcn_readlane((unsigned)rm, w);
        unsigned mhi = __builtin_amdgcn_readlane((unsigned)(rm >> 32), w);
        ull M = ~(((ull)mhi << 32) | (ull)mlo);
        ull km = 0;
        CS8(0) CS8(8) CS8(16) CS8(24) CS8(32) CS8(40) CS8(48) CS8(56)
        const ull* RB = ls + (size_t)(wl * 64 + lg) * 16 + wd;
        ull accB = 0;
#pragma unroll
        for (int t = 0; t < 16; ++t) {
          ull bit = (km >> (4 * t + lg)) & 1ull;
          accB |= RB[(size_t)t * 64] & (0ull - bit);
        }
        accB |= __shfl_xor(accB, 16);
        accB |= __shfl_xor(accB, 32);
        rm |= accB;
      }
    }
    __syncthreads();
  }
  if (wave == 0) scratch[(size_t)b * 64 + lane] = rm;   // keep rm live
}

// ---------------------------------------------------------------- kernel 6 --
// Real nms_scan: unchanged R11 (best-known correct, 45.2us).
__global__ __launch_bounds__(256) void nms_scan_kernel(const ull* __restrict__ sup,
    const ull* __restrict__ validWords, const float* __restrict__ topS,
    const int* __restrict__ topL, float* __restrict__ out) {
  __shared__ ull ls[2][2048];
  int b = blockIdx.x, tid = threadIdx.x;
  int wave = tid >> 6, lane = tid & 63;
  const ull* S = sup + (size_t)b * TOPKP * 16;

  ull rm = 0xFFFFFFFFFFFFFFFFull;
  if (wave == 0 && lane < 16) rm = ~validWords[b * 16 + lane];

  {
    ull s0 = S[tid], s1 = S[tid + 256], s2 = S[tid + 512], s3 = S[tid + 768],
        s4 = S[tid + 1024], s5 = S[tid + 1280], s6 = S[tid + 1536],
        s7 = S[tid + 1792];
    ls[0][tid] = s0;        ls[0][tid + 256] = s1;  ls[0][tid + 512] = s2;
    ls[0][tid + 768] = s3;  ls[0][tid + 1024] = s4; ls[0][tid + 1280] = s5;
    ls[0][tid + 1536] = s6; ls[0][tid + 1792] = s7;
  }
  __syncthreads();

  for (int g = 0; g < 8; ++g) {
    ull s0 = 0, s1 = 0, s2 = 0, s3 = 0, s4 = 0, s5 = 0, s6 = 0, s7 = 0;
    bool st = (g < 7);
    if (st) {
      const ull* src = S + (size_t)(g + 1) * 2048;
      s0 = src[tid];        s1 = src[tid + 256];  s2 = src[tid + 512];
      s3 = src[tid + 768];  s4 = src[tid + 1024]; s5 = src[tid + 1280];
      s6 = src[tid + 1536]; s7 = src[tid + 1792];
    }
    __builtin_amdgcn_sched_barrier(0);

    if (wave == 0) {
      const ull* Bf = ls[g & 1];
      int lg = lane >> 4, wd = lane & 15;
      for (int wl = 0; wl < 2; ++wl) {
        int w = 2 * g + wl;
        ull dg = Bf[(size_t)(wl * 64 + lane) * 16 + w];
        unsigned dlo = (unsigned)dg, dhi = (unsigned)(dg >> 32);
        unsigned mlo = __builtin_amdgcn_readlane((unsigned)rm, w);
        unsigned mhi = __builtin_amdgcn_readlane((unsigned)(rm >> 32), w);
        ull M = ~(((ull)mhi << 32) | (ull)mlo);
        ull km = 0;
        CS8(0) CS8(8) CS8(16) CS8(24) CS8(32) CS8(40) CS8(48) CS8(56)
        const ull* RB = Bf + (size_t)(wl * 64 + lg) * 16 + wd;
        ull accB = 0;
#pragma unroll
        for (int t = 0; t < 16; ++t) {
          ull bit = (km >> (4 * t + lg)) & 1ull;
          accB |= RB[(size_t)t * 64] & (0ull - bit);
        }
        accB |= __shfl_xor(accB, 16);
        accB |= __shfl_xor(accB, 32);
        rm |= accB;
      }
    }

    if (st) {
      ull* dst = ls[(g + 1) & 1];
      dst[tid] = s0;        dst[tid + 256] = s1;  dst[tid + 512] = s2;
      dst[tid + 768] = s3;  dst[tid + 1024] = s4; dst[tid + 1280] = s5;
      dst[tid + 1536] = s6; dst[tid + 1792] = s7;
    }
    __syncthreads();
  }

  if (wave == 0) {
    ull keep_na = ~rm;
    const float* tS = topS + (size_t)b * TOPKP;
    const int*   tL = topL + (size_t)b * TOPKP;
    float* outS = out;
    float* outL = out + BATCH * TOPK;
    float* outK = out + BATCH * TOPK * 6;
    for (int t = 0; t < 16; ++t) {
      int j = t * 64 + lane;
      ull kw = __shfl(keep_na, t);
      if (j < TOPK) {
        bool kp = (kw >> lane) & 1ull;
        outS[(size_t)b * TOPK + j] = kp ? tS[j] : 0.f;
        outL[(size_t)b * TOPK + j] = kp ? (float)tL[j] : 0.f;
        outK[(size_t)b * TOPK + j] = kp ? 1.f : 0.f;
      }
    }
  }
}
#undef CS8
#undef CS

// -------------------------------------------------------------------- host --
extern "C" void kernel_launch(void* const* d_in, const int* in_sizes, int n_in,
                              void* d_out, int out_size, void* d_ws, size_t ws_size,
                              hipStream_t stream) {
  Ptrs p;
  for (int l = 0; l < 5; ++l) {
    p.cls[l] = (const float*)d_in[l];
    p.reg[l] = (const float*)d_in[5 + l];
    p.ctr[l] = (const float*)d_in[10 + l];
  }
  char* ws = (char*)d_ws;
  size_t o = 0;
  auto alloc = [&](size_t bytes) -> void* {
    void* r = ws + o; o += (bytes + 255) & ~(size_t)255; return r;
  };
  ull*   keys       = (ull*)  alloc((size_t)BATCH * NPAD * 8);
  int*   labels     = (int*)  alloc((size_t)BATCH * NLOC * 4);
  float* boxes      = (float*)alloc((size_t)BATCH * NLOC * 16);
  ull*   runs       = (ull*)  alloc((size_t)BATCH * NCHUNK * TOPKP * 8);
  ull*   runs2      = (ull*)  alloc((size_t)BATCH * NCHUNK * TOPKP * 8);
  ull*   topkeys    = (ull*)  alloc((size_t)BATCH * TOPKP * 8);
  float* topS       = (float*)alloc((size_t)BATCH * TOPKP * 4);
  int*   topL       = (int*)  alloc((size_t)BATCH * TOPKP * 4);
  float* topOB      = (float*)alloc((size_t)BATCH * TOPKP * 16);
  ull*   validWords = (ull*)  alloc((size_t)BATCH * 16 * 8);
  ull*   sup        = (ull*)  alloc((size_t)BATCH * TOPKP * 16 * 8);
  ull*   probeA     = (ull*)  alloc((size_t)BATCH * 256 * 8);
  ull*   probeB     = (ull*)  alloc((size_t)BATCH * 64 * 8);

  float* out = (float*)d_out;
  float* outBoxes = out + 2 * BATCH * TOPK;   // offset 32000

  hipLaunchKernelGGL(score_kernel, dim3((BATCH * NPAD + 255) / 256), dim3(256), 0, stream,
                     p, keys, labels, boxes);
  hipLaunchKernelGGL(chunk_sort_kernel, dim3(BATCH * NCHUNK), dim3(512), 0, stream,
                     keys, runs);
  hipLaunchKernelGGL(merge_level_kernel, dim3(BATCH * 5), dim3(512), 0, stream,
                     runs, runs2, 4, 1, NCHUNK, NCHUNK);
  hipLaunchKernelGGL(merge_level_kernel, dim3(BATCH * 3), dim3(512), 0, stream,
                     runs2, runs, 2, 1, NCHUNK, NCHUNK);
  hipLaunchKernelGGL(merge_level_kernel, dim3(BATCH * 2), dim3(512), 0, stream,
                     runs, runs2, 1, 1, NCHUNK, NCHUNK);
  hipLaunchKernelGGL(merge_level_kernel, dim3(BATCH * 1), dim3(512), 0, stream,
                     runs2, topkeys, 1, 0, NCHUNK, 1);
  hipLaunchKernelGGL(gather_kernel, dim3(BATCH), dim3(256), 0, stream,
                     topkeys, labels, boxes, topS, topL, topOB, validWords, outBoxes);
  hipLaunchKernelGGL(sup_kernel, dim3(BATCH * TOPK), dim3(1024), 0, stream,
                     topOB, sup);
  // ---- ablation probes (write only to ws scratch) ----
  hipLaunchKernelGGL(nms_probe_load, dim3(BATCH), dim3(256), 0, stream,
                     sup, probeA);
  hipLaunchKernelGGL(nms_probe_chain, dim3(BATCH), dim3(256), 0, stream,
                     sup, validWords, probeB);
  // ---- real scan (unchanged R11) ----
  hipLaunchKernelGGL(nms_scan_kernel, dim3(BATCH), dim3(256), 0, stream,
                     sup, validWords, topS, topL, out);
}

// Round 13
// 231.125 us; speedup vs baseline: 1.2601x; 1.2601x over previous
//
#include <hip/hip_runtime.h>
#include <cstdint>

// FCOS detection post-process for MI355X.
// Pipeline: score/box decode -> per-image exact top-1000 (bitonic chunk sort +
// tree merge) -> suppression bitmask -> sparse greedy NMS scan -> outputs.

typedef unsigned long long ull;

#define BATCH 16
#define NLOC 17064      // total FPN locations per image
#define NPAD 18432      // padded to 9 * 2048
#define NCHUNK 9
#define CHUNK 2048
#define TOPK 1000
#define TOPKP 1024
#define NCLS 80
#define SCORE_THR 0.05f
#define IOU_THR 0.6f

struct Ptrs { const float* cls[5]; const float* reg[5]; const float* ctr[5]; };

// ---------------------------------------------------------------- kernel 1 --
__global__ __launch_bounds__(256) void score_kernel(Ptrs p, ull* __restrict__ keys,
                                                    int* __restrict__ labels,
                                                    float* __restrict__ boxes) {
  int idx = blockIdx.x * 256 + threadIdx.x;
  if (idx >= BATCH * NPAD) return;
  int b = idx / NPAD, n = idx - b * NPAD;
  if (n >= NLOC) { keys[idx] = 0ull; return; }

  int lvl, off, lw, st, H;
  if (n < 12800)      { lvl=0; off=0;     lw=7; st=8;   H=100; }
  else if (n < 16000) { lvl=1; off=12800; lw=6; st=16;  H=50;  }
  else if (n < 16800) { lvl=2; off=16000; lw=5; st=32;  H=25;  }
  else if (n < 17008) { lvl=3; off=16800; lw=4; st=64;  H=13;  }
  else                { lvl=4; off=17008; lw=3; st=128; H=7;   }
  int hw = n - off;
  int w = hw & ((1 << lw) - 1), h = hw >> lw;
  int HW = H << lw;
  float fs = (float)st, half = fs * 0.5f;
  float x = (float)w * fs + half, y = (float)h * fs + half;

  const float* cb = p.cls[lvl] + (size_t)b * NCLS * HW + hw;
  float best = cb[0]; int bi = 0;
  for (int c = 1; c < NCLS; ++c) {
    float v = cb[(size_t)c * HW];
    if (v > best) { best = v; bi = c; }   // strict > keeps first max (jnp.argmax)
  }
  const float* rb = p.reg[lvl] + (size_t)b * 4 * HW + hw;
  float r0 = rb[0], r1 = rb[HW], r2 = rb[2 * (size_t)HW], r3 = rb[3 * (size_t)HW];
  float ct = p.ctr[lvl][(size_t)b * HW + hw];

  float pcls = 1.f / (1.f + expf(-best));
  float pctr = 1.f / (1.f + expf(-ct));
  float score = sqrtf(pcls * pctr);

  keys[idx] = ((ull)__float_as_uint(score) << 32) | (ull)(0xFFFFFFFFu - (unsigned)n);
  labels[(size_t)b * NLOC + n] = bi + 1;
  float* bx = boxes + ((size_t)b * NLOC + n) * 4;
  bx[0] = x - r0; bx[1] = y - r1; bx[2] = x + r2; bx[3] = y + r3;
}

// ---------------------------------------------------------------- kernel 2 --
__global__ __launch_bounds__(512) void chunk_sort_kernel(const ull* __restrict__ keys,
                                                         ull* __restrict__ runs) {
  __shared__ ull s[CHUNK];
  int b = blockIdx.x / NCHUNK, c = blockIdx.x % NCHUNK;
  const ull* src = keys + (size_t)b * NPAD + (size_t)c * CHUNK;
  for (int i = threadIdx.x; i < CHUNK; i += 512) s[i] = src[i];
  __syncthreads();
  for (int k = 2; k <= CHUNK; k <<= 1) {
    for (int j = k >> 1; j > 0; j >>= 1) {
      for (int t = threadIdx.x; t < CHUNK / 2; t += 512) {
        int i = ((t & ~(j - 1)) << 1) | (t & (j - 1));
        int ixj = i | j;
        bool desc = (i & k) == 0;
        ull a = s[i], bb = s[ixj];
        bool sw = desc ? (a < bb) : (a > bb);
        if (sw) { s[i] = bb; s[ixj] = a; }
      }
      __syncthreads();
    }
  }
  ull* dst = runs + ((size_t)b * NCHUNK + c) * TOPKP;
  for (int i = threadIdx.x; i < TOPKP; i += 512) dst[i] = s[i];
}

// ---------------------------------------------------------------- kernel 3 --
__global__ __launch_bounds__(512) void merge_level_kernel(const ull* __restrict__ src,
    ull* __restrict__ dst, int npairs, int carry, int srcRPI, int dstRPI) {
  int per = npairs + carry;
  int b = blockIdx.x / per, p = blockIdx.x % per;
  const ull* sb = src + (size_t)b * srcRPI * TOPKP;
  ull* db = dst + (size_t)b * dstRPI * TOPKP;
  int tid = threadIdx.x;
  if (p >= npairs) {   // carry: copy last odd run through
    for (int i = tid; i < TOPKP; i += 512)
      db[(size_t)p * TOPKP + i] = sb[(size_t)(2 * npairs) * TOPKP + i];
    return;
  }
  __shared__ ull m[TOPKP];
  const ull* A = sb + (size_t)(2 * p) * TOPKP;
  const ull* B = sb + (size_t)(2 * p + 1) * TOPKP;
  for (int i = tid; i < TOPKP; i += 512) {
    ull a = A[i], c = B[TOPKP - 1 - i];
    m[i] = a > c ? a : c;
  }
  __syncthreads();
  for (int j = TOPKP / 2; j > 0; j >>= 1) {
    for (int t = tid; t < TOPKP / 2; t += 512) {
      int i = ((t & ~(j - 1)) << 1) | (t & (j - 1));
      int ixj = i | j;
      ull a = m[i], c = m[ixj];
      if (a < c) { m[i] = c; m[ixj] = a; }
    }
    __syncthreads();
  }
  for (int i = tid; i < TOPKP; i += 512) db[(size_t)p * TOPKP + i] = m[i];
}

// ---------------------------------------------------------------- kernel 4 --
__global__ __launch_bounds__(256) void gather_kernel(const ull* __restrict__ topkeys,
    const int* __restrict__ labels, const float* __restrict__ boxes,
    float* __restrict__ topS, int* __restrict__ topL, float* __restrict__ topOB,
    ull* __restrict__ validWords, float* __restrict__ outBoxes) {
  __shared__ float red[256];
  __shared__ float s_cmax;
  int b = blockIdx.x, tid = threadIdx.x;
  float lmax = 0.f;
  for (int k = tid; k < TOPKP; k += 256) {
    ull key = topkeys[(size_t)b * TOPKP + k];
    float sc = 0.f; int lb = 0;
    float b0 = 0.f, b1 = 0.f, b2 = 0.f, b3 = 0.f;
    bool inR = (k < TOPK);
    if (inR) {
      sc = __uint_as_float((unsigned)(key >> 32));
      unsigned n = 0xFFFFFFFFu - (unsigned)(key & 0xFFFFFFFFull);
      lb = labels[(size_t)b * NLOC + n];
      const float* bp = boxes + ((size_t)b * NLOC + n) * 4;
      b0 = bp[0]; b1 = bp[1]; b2 = bp[2]; b3 = bp[3];
      float* ob = outBoxes + ((size_t)b * TOPK + k) * 4;
      ob[0] = b0; ob[1] = b1; ob[2] = b2; ob[3] = b3;
    }
    topS[(size_t)b * TOPKP + k] = sc;
    topL[(size_t)b * TOPKP + k] = lb;
    float* tb = topOB + ((size_t)b * TOPKP + k) * 4;
    tb[0] = b0; tb[1] = b1; tb[2] = b2; tb[3] = b3;
    bool valid = inR && (sc > SCORE_THR);
    if (valid) lmax = fmaxf(lmax, fmaxf(fmaxf(b0, b1), fmaxf(b2, b3)));
    ull vb = __ballot(valid ? 1 : 0);
    if ((tid & 63) == 0) validWords[b * 16 + (k >> 6)] = vb;
  }
  red[tid] = lmax;
  __syncthreads();
  for (int sft = 128; sft > 0; sft >>= 1) {
    if (tid < sft) red[tid] = fmaxf(red[tid], red[tid + sft]);
    __syncthreads();
  }
  if (tid == 0) s_cmax = red[0];
  __syncthreads();
  float offb = s_cmax + 1.0f;
  for (int k = tid; k < TOPKP; k += 256) {
    float off = (float)topL[(size_t)b * TOPKP + k] * offb;
    float* tb = topOB + ((size_t)b * TOPKP + k) * 4;
    tb[0] += off; tb[1] += off; tb[2] += off; tb[3] += off;
  }
}

// ---------------------------------------------------------------- kernel 5 --
__global__ __launch_bounds__(1024) void sup_kernel(const float* __restrict__ topOB,
                                                   ull* __restrict__ sup) {
  int bid = blockIdx.x;
  int b = bid / TOPK, i = bid - b * TOPK;
  int j = threadIdx.x;
  const float4* OB = (const float4*)topOB + (size_t)b * TOPKP;
  float4 A = OB[i];
  float aw = fmaxf(A.z - A.x, 0.f), ah = fmaxf(A.w - A.y, 0.f);
  float areaA = aw * ah;
  bool bit = false;
  if (j > i && j < TOPK) {
    float4 Bx = OB[j];
    float bw = fmaxf(Bx.z - Bx.x, 0.f), bh = fmaxf(Bx.w - Bx.y, 0.f);
    float areaB = bw * bh;
    float ix1 = fmaxf(A.x, Bx.x), iy1 = fmaxf(A.y, Bx.y);
    float ix2 = fminf(A.z, Bx.z), iy2 = fminf(A.w, Bx.w);
    float inter = fmaxf(ix2 - ix1, 0.f) * fmaxf(iy2 - iy1, 0.f);
    float uni = areaA + areaB - inter;
    float iou = inter / fmaxf(uni, 1e-9f);
    bit = iou > IOU_THR;
  }
  ull m = __ballot(bit ? 1 : 0);
  if ((j & 63) == 0) sup[((size_t)b * TOPKP + i) * 16 + (j >> 6)] = m;
}

// ---------------------------------------------------------------- kernel 6 --
// Sparse greedy scan. R12 ablation: load path ~5us, so the 1024-step serial
// chain itself is the ~40us wall (~105 cyc/step: readlane->SALU hazards +
// 64-bit SALU cracking, single-wave serial issue). Fix: greedy state only
// changes at candidates with a NONZERO suppression row -- rare (~tens/1000
// for random same-class boxes). Per span: nz = ballot(diag != 0); iterate
// cand = nz & ~R, k = ctz(cand), R |= d[k] (variable-index readlane) --
// provably identical to the sequential scan (picks increase; R at pick time
// equals the full scan's removed set; zero-row candidates never change
// state). km = ~R. Iterations/span ~1-3 instead of 64. Staging/phase B
// unchanged from R11. Poisoned sup rows 1000-1023: R starts ~valid so they
// are never picked and never ORed.
__global__ __launch_bounds__(256) void nms_scan_kernel(const ull* __restrict__ sup,
    const ull* __restrict__ validWords, const float* __restrict__ topS,
    const int* __restrict__ topL, float* __restrict__ out) {
  __shared__ ull ls[2][2048];
  int b = blockIdx.x, tid = threadIdx.x;
  int wave = tid >> 6, lane = tid & 63;
  const ull* S = sup + (size_t)b * TOPKP * 16;

  ull rm = 0xFFFFFFFFFFFFFFFFull;
  if (wave == 0 && lane < 16) rm = ~validWords[b * 16 + lane];

  {
    ull s0 = S[tid], s1 = S[tid + 256], s2 = S[tid + 512], s3 = S[tid + 768],
        s4 = S[tid + 1024], s5 = S[tid + 1280], s6 = S[tid + 1536],
        s7 = S[tid + 1792];
    ls[0][tid] = s0;        ls[0][tid + 256] = s1;  ls[0][tid + 512] = s2;
    ls[0][tid + 768] = s3;  ls[0][tid + 1024] = s4; ls[0][tid + 1280] = s5;
    ls[0][tid + 1536] = s6; ls[0][tid + 1792] = s7;
  }
  __syncthreads();

  for (int g = 0; g < 8; ++g) {
    ull s0 = 0, s1 = 0, s2 = 0, s3 = 0, s4 = 0, s5 = 0, s6 = 0, s7 = 0;
    bool st = (g < 7);
    if (st) {
      const ull* src = S + (size_t)(g + 1) * 2048;
      s0 = src[tid];        s1 = src[tid + 256];  s2 = src[tid + 512];
      s3 = src[tid + 768];  s4 = src[tid + 1024]; s5 = src[tid + 1280];
      s6 = src[tid + 1536]; s7 = src[tid + 1792];
    }
    __builtin_amdgcn_sched_barrier(0);   // pin load issue before compute

    if (wave == 0) {
      const ull* Bf = ls[g & 1];
      int lg = lane >> 4, wd = lane & 15;
      for (int wl = 0; wl < 2; ++wl) {
        int w = 2 * g + wl;
        ull dg = Bf[(size_t)(wl * 64 + lane) * 16 + w];   // diag of row w*64+lane
        unsigned dlo = (unsigned)dg, dhi = (unsigned)(dg >> 32);
        unsigned mlo = __builtin_amdgcn_readlane((unsigned)rm, w);
        unsigned mhi = __builtin_amdgcn_readlane((unsigned)(rm >> 32), w);
        ull M = ~(((ull)mhi << 32) | (ull)mlo);   // alive mask of span w
        // ---- sparse greedy core ----
        ull nz = __ballot(dg != 0ull);    // rows that can suppress anything
        ull R = ~M;                       // removed set
        ull cand;
        while ((cand = nz & ~R) != 0ull) {
          int k = (int)__builtin_ctzll(cand);   // lowest alive suppressor
          unsigned rl = __builtin_amdgcn_readlane(dlo, k);
          unsigned rh = __builtin_amdgcn_readlane(dhi, k);
          R |= (((ull)rh << 32) | (ull)rl);
          nz &= ~(1ull << k);
        }
        ull km = ~R;                      // kept mask
        // ---- phase B: OR kept rows' words into owners ----
        const ull* RB = Bf + (size_t)(wl * 64 + lg) * 16 + wd;
        ull accB = 0;
#pragma unroll
        for (int t = 0; t < 16; ++t) {
          ull bit = (km >> (4 * t + lg)) & 1ull;
          accB |= RB[(size_t)t * 64] & (0ull - bit);
        }
        accB |= __shfl_xor(accB, 16);
        accB |= __shfl_xor(accB, 32);
        rm |= accB;
      }
    }

    if (st) {
      ull* dst = ls[(g + 1) & 1];
      dst[tid] = s0;        dst[tid + 256] = s1;  dst[tid + 512] = s2;
      dst[tid + 768] = s3;  dst[tid + 1024] = s4; dst[tid + 1280] = s5;
      dst[tid + 1536] = s6; dst[tid + 1792] = s7;
    }
    __syncthreads();
  }

  if (wave == 0) {
    ull keep_na = ~rm;
    const float* tS = topS + (size_t)b * TOPKP;
    const int*   tL = topL + (size_t)b * TOPKP;
    float* outS = out;
    float* outL = out + BATCH * TOPK;
    float* outK = out + BATCH * TOPK * 6;
    for (int t = 0; t < 16; ++t) {
      int j = t * 64 + lane;
      ull kw = __shfl(keep_na, t);
      if (j < TOPK) {
        bool kp = (kw >> lane) & 1ull;
        outS[(size_t)b * TOPK + j] = kp ? tS[j] : 0.f;
        outL[(size_t)b * TOPK + j] = kp ? (float)tL[j] : 0.f;
        outK[(size_t)b * TOPK + j] = kp ? 1.f : 0.f;
      }
    }
  }
}

// -------------------------------------------------------------------- host --
extern "C" void kernel_launch(void* const* d_in, const int* in_sizes, int n_in,
                              void* d_out, int out_size, void* d_ws, size_t ws_size,
                              hipStream_t stream) {
  Ptrs p;
  for (int l = 0; l < 5; ++l) {
    p.cls[l] = (const float*)d_in[l];
    p.reg[l] = (const float*)d_in[5 + l];
    p.ctr[l] = (const float*)d_in[10 + l];
  }
  char* ws = (char*)d_ws;
  size_t o = 0;
  auto alloc = [&](size_t bytes) -> void* {
    void* r = ws + o; o += (bytes + 255) & ~(size_t)255; return r;
  };
  ull*   keys       = (ull*)  alloc((size_t)BATCH * NPAD * 8);
  int*   labels     = (int*)  alloc((size_t)BATCH * NLOC * 4);
  float* boxes      = (float*)alloc((size_t)BATCH * NLOC * 16);
  ull*   runs       = (ull*)  alloc((size_t)BATCH * NCHUNK * TOPKP * 8);
  ull*   runs2      = (ull*)  alloc((size_t)BATCH * NCHUNK * TOPKP * 8);
  ull*   topkeys    = (ull*)  alloc((size_t)BATCH * TOPKP * 8);
  float* topS       = (float*)alloc((size_t)BATCH * TOPKP * 4);
  int*   topL       = (int*)  alloc((size_t)BATCH * TOPKP * 4);
  float* topOB      = (float*)alloc((size_t)BATCH * TOPKP * 16);
  ull*   validWords = (ull*)  alloc((size_t)BATCH * 16 * 8);
  ull*   sup        = (ull*)  alloc((size_t)BATCH * TOPKP * 16 * 8);

  float* out = (float*)d_out;
  float* outBoxes = out + 2 * BATCH * TOPK;   // offset 32000

  hipLaunchKernelGGL(score_kernel, dim3((BATCH * NPAD + 255) / 256), dim3(256), 0, stream,
                     p, keys, labels, boxes);
  hipLaunchKernelGGL(chunk_sort_kernel, dim3(BATCH * NCHUNK), dim3(512), 0, stream,
                     keys, runs);
  hipLaunchKernelGGL(merge_level_kernel, dim3(BATCH * 5), dim3(512), 0, stream,
                     runs, runs2, 4, 1, NCHUNK, NCHUNK);
  hipLaunchKernelGGL(merge_level_kernel, dim3(BATCH * 3), dim3(512), 0, stream,
                     runs2, runs, 2, 1, NCHUNK, NCHUNK);
  hipLaunchKernelGGL(merge_level_kernel, dim3(BATCH * 2), dim3(512), 0, stream,
                     runs, runs2, 1, 1, NCHUNK, NCHUNK);
  hipLaunchKernelGGL(merge_level_kernel, dim3(BATCH * 1), dim3(512), 0, stream,
                     runs2, topkeys, 1, 0, NCHUNK, 1);
  hipLaunchKernelGGL(gather_kernel, dim3(BATCH), dim3(256), 0, stream,
                     topkeys, labels, boxes, topS, topL, topOB, validWords, outBoxes);
  hipLaunchKernelGGL(sup_kernel, dim3(BATCH * TOPK), dim3(1024), 0, stream,
                     topOB, sup);
  hipLaunchKernelGGL(nms_scan_kernel, dim3(BATCH), dim3(256), 0, stream,
                     sup, validWords, topS, topL, out);
}

// Round 14
// 229.519 us; speedup vs baseline: 1.2690x; 1.0070x over previous
//
#include <hip/hip_runtime.h>
#include <cstdint>

// FCOS detection post-process for MI355X.
// Pipeline (5 dispatches): score/box decode -> per-image bitonic chunk sort ->
// fused merge-tree+gather -> suppression bitmask -> sparse greedy NMS -> out.
// R13 lesson: no kernel >40us but 10 serial graph nodes summed to 231us with
// ~95us of modeled work -> ~10-12us/node overhead. This round fuses the 4
// merge levels + gather (5 small-grid nodes) into ONE 16-block kernel.

typedef unsigned long long ull;

#define BATCH 16
#define NLOC 17064      // total FPN locations per image
#define NPAD 18432      // padded to 9 * 2048
#define NCHUNK 9
#define CHUNK 2048
#define TOPK 1000
#define TOPKP 1024
#define NCLS 80
#define SCORE_THR 0.05f
#define IOU_THR 0.6f

struct Ptrs { const float* cls[5]; const float* reg[5]; const float* ctr[5]; };

// ---------------------------------------------------------------- kernel 1 --
__global__ __launch_bounds__(256) void score_kernel(Ptrs p, ull* __restrict__ keys,
                                                    int* __restrict__ labels,
                                                    float* __restrict__ boxes) {
  int idx = blockIdx.x * 256 + threadIdx.x;
  if (idx >= BATCH * NPAD) return;
  int b = idx / NPAD, n = idx - b * NPAD;
  if (n >= NLOC) { keys[idx] = 0ull; return; }

  int lvl, off, lw, st, H;
  if (n < 12800)      { lvl=0; off=0;     lw=7; st=8;   H=100; }
  else if (n < 16000) { lvl=1; off=12800; lw=6; st=16;  H=50;  }
  else if (n < 16800) { lvl=2; off=16000; lw=5; st=32;  H=25;  }
  else if (n < 17008) { lvl=3; off=16800; lw=4; st=64;  H=13;  }
  else                { lvl=4; off=17008; lw=3; st=128; H=7;   }
  int hw = n - off;
  int w = hw & ((1 << lw) - 1), h = hw >> lw;
  int HW = H << lw;
  float fs = (float)st, half = fs * 0.5f;
  float x = (float)w * fs + half, y = (float)h * fs + half;

  const float* cb = p.cls[lvl] + (size_t)b * NCLS * HW + hw;
  float best = cb[0]; int bi = 0;
  for (int c = 1; c < NCLS; ++c) {
    float v = cb[(size_t)c * HW];
    if (v > best) { best = v; bi = c; }   // strict > keeps first max (jnp.argmax)
  }
  const float* rb = p.reg[lvl] + (size_t)b * 4 * HW + hw;
  float r0 = rb[0], r1 = rb[HW], r2 = rb[2 * (size_t)HW], r3 = rb[3 * (size_t)HW];
  float ct = p.ctr[lvl][(size_t)b * HW + hw];

  float pcls = 1.f / (1.f + expf(-best));
  float pctr = 1.f / (1.f + expf(-ct));
  float score = sqrtf(pcls * pctr);

  keys[idx] = ((ull)__float_as_uint(score) << 32) | (ull)(0xFFFFFFFFu - (unsigned)n);
  labels[(size_t)b * NLOC + n] = bi + 1;
  float* bx = boxes + ((size_t)b * NLOC + n) * 4;
  bx[0] = x - r0; bx[1] = y - r1; bx[2] = x + r2; bx[3] = y + r3;
}

// ---------------------------------------------------------------- kernel 2 --
__global__ __launch_bounds__(512) void chunk_sort_kernel(const ull* __restrict__ keys,
                                                         ull* __restrict__ runs) {
  __shared__ ull s[CHUNK];
  int b = blockIdx.x / NCHUNK, c = blockIdx.x % NCHUNK;
  const ull* src = keys + (size_t)b * NPAD + (size_t)c * CHUNK;
  for (int i = threadIdx.x; i < CHUNK; i += 512) s[i] = src[i];
  __syncthreads();
  for (int k = 2; k <= CHUNK; k <<= 1) {
    for (int j = k >> 1; j > 0; j >>= 1) {
      for (int t = threadIdx.x; t < CHUNK / 2; t += 512) {
        int i = ((t & ~(j - 1)) << 1) | (t & (j - 1));
        int ixj = i | j;
        bool desc = (i & k) == 0;
        ull a = s[i], bb = s[ixj];
        bool sw = desc ? (a < bb) : (a > bb);
        if (sw) { s[i] = bb; s[ixj] = a; }
      }
      __syncthreads();
    }
  }
  ull* dst = runs + ((size_t)b * NCHUNK + c) * TOPKP;
  for (int i = threadIdx.x; i < TOPKP; i += 512) dst[i] = s[i];
}

// ---------------------------------------------------------------- kernel 3 --
// Fused merge-tree + gather, one block per image. Fold the 9 descending
// 1024-runs serially in LDS: per merge, pass 1 consumes the incoming run
// REVERSED straight from global (m[i] = max(m[i], B[1023-i]) -- top half of
// the 2048 bitonic merge), then a 10-pass descending clean of the bitonic
// 1024 (identical math to R2's merge_level, verified absmax 0.0 since R2).
// Then the gather phase runs in-block, reading topkeys from LDS: decode,
// scatter-gather labels/boxes, coord_max reduce, class-offset, validWords.
__global__ __launch_bounds__(512) void merge_gather_kernel(
    const ull* __restrict__ runs, const int* __restrict__ labels,
    const float* __restrict__ boxes, float* __restrict__ topS,
    int* __restrict__ topL, float* __restrict__ topOB,
    ull* __restrict__ validWords, float* __restrict__ outBoxes) {
  __shared__ ull m[TOPKP];
  __shared__ float red[512];
  __shared__ float s_cmax;
  int b = blockIdx.x, tid = threadIdx.x;
  const ull* rbase = runs + (size_t)b * NCHUNK * TOPKP;

  for (int i = tid; i < TOPKP; i += 512) m[i] = rbase[i];
  __syncthreads();
  for (int r = 1; r < NCHUNK; ++r) {
    // pass j=1024: top half = max(m[i], runB[1023-i]) (runB read reversed)
    const ull* B = rbase + (size_t)r * TOPKP;
    for (int i = tid; i < TOPKP; i += 512) {
      ull a = m[i], c = B[TOPKP - 1 - i];
      if (c > a) m[i] = c;
    }
    __syncthreads();
    // descending bitonic clean of the (bitonic) top half
    for (int j = TOPKP / 2; j > 0; j >>= 1) {
      for (int t = tid; t < TOPKP / 2; t += 512) {
        int i = ((t & ~(j - 1)) << 1) | (t & (j - 1));
        int ixj = i | j;
        ull a = m[i], c = m[ixj];
        if (a < c) { m[i] = c; m[ixj] = a; }
      }
      __syncthreads();
    }
  }

  // ---- gather phase (topkeys = m[0..1023] in LDS) ----
  float lmax = 0.f;   // reference maxes over where(valid, bx, 0) -> zeros incl.
  for (int k = tid; k < TOPKP; k += 512) {
    ull key = m[k];
    float sc = 0.f; int lb = 0;
    float b0 = 0.f, b1 = 0.f, b2 = 0.f, b3 = 0.f;
    bool inR = (k < TOPK);
    if (inR) {
      sc = __uint_as_float((unsigned)(key >> 32));
      unsigned n = 0xFFFFFFFFu - (unsigned)(key & 0xFFFFFFFFull);
      lb = labels[(size_t)b * NLOC + n];
      const float* bp = boxes + ((size_t)b * NLOC + n) * 4;
      b0 = bp[0]; b1 = bp[1]; b2 = bp[2]; b3 = bp[3];
      float* ob = outBoxes + ((size_t)b * TOPK + k) * 4;
      ob[0] = b0; ob[1] = b1; ob[2] = b2; ob[3] = b3;   // boxes out: all 1000
    }
    topS[(size_t)b * TOPKP + k] = sc;
    topL[(size_t)b * TOPKP + k] = lb;
    float* tb = topOB + ((size_t)b * TOPKP + k) * 4;
    tb[0] = b0; tb[1] = b1; tb[2] = b2; tb[3] = b3;
    bool valid = inR && (sc > SCORE_THR);
    if (valid) lmax = fmaxf(lmax, fmaxf(fmaxf(b0, b1), fmaxf(b2, b3)));
    ull vb = __ballot(valid ? 1 : 0);
    if ((tid & 63) == 0) validWords[b * 16 + (k >> 6)] = vb;
  }
  red[tid] = lmax;
  __syncthreads();
  for (int sft = 256; sft > 0; sft >>= 1) {
    if (tid < sft) red[tid] = fmaxf(red[tid], red[tid + sft]);
    __syncthreads();
  }
  if (tid == 0) s_cmax = red[0];
  __syncthreads();
  float offb = s_cmax + 1.0f;
  for (int k = tid; k < TOPKP; k += 512) {
    float off = (float)topL[(size_t)b * TOPKP + k] * offb;   // class-offset
    float* tb = topOB + ((size_t)b * TOPKP + k) * 4;
    tb[0] += off; tb[1] += off; tb[2] += off; tb[3] += off;
  }
}

// ---------------------------------------------------------------- kernel 4 --
__global__ __launch_bounds__(1024) void sup_kernel(const float* __restrict__ topOB,
                                                   ull* __restrict__ sup) {
  int bid = blockIdx.x;
  int b = bid / TOPK, i = bid - b * TOPK;
  int j = threadIdx.x;
  const float4* OB = (const float4*)topOB + (size_t)b * TOPKP;
  float4 A = OB[i];
  float aw = fmaxf(A.z - A.x, 0.f), ah = fmaxf(A.w - A.y, 0.f);
  float areaA = aw * ah;
  bool bit = false;
  if (j > i && j < TOPK) {
    float4 Bx = OB[j];
    float bw = fmaxf(Bx.z - Bx.x, 0.f), bh = fmaxf(Bx.w - Bx.y, 0.f);
    float areaB = bw * bh;
    float ix1 = fmaxf(A.x, Bx.x), iy1 = fmaxf(A.y, Bx.y);
    float ix2 = fminf(A.z, Bx.z), iy2 = fminf(A.w, Bx.w);
    float inter = fmaxf(ix2 - ix1, 0.f) * fmaxf(iy2 - iy1, 0.f);
    float uni = areaA + areaB - inter;
    float iou = inter / fmaxf(uni, 1e-9f);
    bit = iou > IOU_THR;
  }
  ull m = __ballot(bit ? 1 : 0);
  if ((j & 63) == 0) sup[((size_t)b * TOPKP + i) * 16 + (j >> 6)] = m;
}

// ---------------------------------------------------------------- kernel 5 --
// Sparse greedy scan (R13, 45->23us): greedy state only changes at candidates
// with a NONZERO suppression row. Per span: nz = ballot(diag != 0); iterate
// cand = nz & ~R, k = ctz(cand), R |= d[k] -- provably identical to the
// sequential scan. Staging: R11 reg-batched issue-early/write-late.
__global__ __launch_bounds__(256) void nms_scan_kernel(const ull* __restrict__ sup,
    const ull* __restrict__ validWords, const float* __restrict__ topS,
    const int* __restrict__ topL, float* __restrict__ out) {
  __shared__ ull ls[2][2048];
  int b = blockIdx.x, tid = threadIdx.x;
  int wave = tid >> 6, lane = tid & 63;
  const ull* S = sup + (size_t)b * TOPKP * 16;

  ull rm = 0xFFFFFFFFFFFFFFFFull;
  if (wave == 0 && lane < 16) rm = ~validWords[b * 16 + lane];

  {
    ull s0 = S[tid], s1 = S[tid + 256], s2 = S[tid + 512], s3 = S[tid + 768],
        s4 = S[tid + 1024], s5 = S[tid + 1280], s6 = S[tid + 1536],
        s7 = S[tid + 1792];
    ls[0][tid] = s0;        ls[0][tid + 256] = s1;  ls[0][tid + 512] = s2;
    ls[0][tid + 768] = s3;  ls[0][tid + 1024] = s4; ls[0][tid + 1280] = s5;
    ls[0][tid + 1536] = s6; ls[0][tid + 1792] = s7;
  }
  __syncthreads();

  for (int g = 0; g < 8; ++g) {
    ull s0 = 0, s1 = 0, s2 = 0, s3 = 0, s4 = 0, s5 = 0, s6 = 0, s7 = 0;
    bool st = (g < 7);
    if (st) {
      const ull* src = S + (size_t)(g + 1) * 2048;
      s0 = src[tid];        s1 = src[tid + 256];  s2 = src[tid + 512];
      s3 = src[tid + 768];  s4 = src[tid + 1024]; s5 = src[tid + 1280];
      s6 = src[tid + 1536]; s7 = src[tid + 1792];
    }
    __builtin_amdgcn_sched_barrier(0);   // pin load issue before compute

    if (wave == 0) {
      const ull* Bf = ls[g & 1];
      int lg = lane >> 4, wd = lane & 15;
      for (int wl = 0; wl < 2; ++wl) {
        int w = 2 * g + wl;
        ull dg = Bf[(size_t)(wl * 64 + lane) * 16 + w];   // diag of row w*64+lane
        unsigned dlo = (unsigned)dg, dhi = (unsigned)(dg >> 32);
        unsigned mlo = __builtin_amdgcn_readlane((unsigned)rm, w);
        unsigned mhi = __builtin_amdgcn_readlane((unsigned)(rm >> 32), w);
        ull M = ~(((ull)mhi << 32) | (ull)mlo);   // alive mask of span w
        // ---- sparse greedy core ----
        ull nz = __ballot(dg != 0ull);
        ull R = ~M;
        ull cand;
        while ((cand = nz & ~R) != 0ull) {
          int k = (int)__builtin_ctzll(cand);
          unsigned rl = __builtin_amdgcn_readlane(dlo, k);
          unsigned rh = __builtin_amdgcn_readlane(dhi, k);
          R |= (((ull)rh << 32) | (ull)rl);
          nz &= ~(1ull << k);
        }
        ull km = ~R;                      // kept mask
        // ---- phase B: OR kept rows' words into owners ----
        const ull* RB = Bf + (size_t)(wl * 64 + lg) * 16 + wd;
        ull accB = 0;
#pragma unroll
        for (int t = 0; t < 16; ++t) {
          ull bit = (km >> (4 * t + lg)) & 1ull;
          accB |= RB[(size_t)t * 64] & (0ull - bit);
        }
        accB |= __shfl_xor(accB, 16);
        accB |= __shfl_xor(accB, 32);
        rm |= accB;
      }
    }

    if (st) {
      ull* dst = ls[(g + 1) & 1];
      dst[tid] = s0;        dst[tid + 256] = s1;  dst[tid + 512] = s2;
      dst[tid + 768] = s3;  dst[tid + 1024] = s4; dst[tid + 1280] = s5;
      dst[tid + 1536] = s6; dst[tid + 1792] = s7;
    }
    __syncthreads();
  }

  if (wave == 0) {
    ull keep_na = ~rm;
    const float* tS = topS + (size_t)b * TOPKP;
    const int*   tL = topL + (size_t)b * TOPKP;
    float* outS = out;
    float* outL = out + BATCH * TOPK;
    float* outK = out + BATCH * TOPK * 6;
    for (int t = 0; t < 16; ++t) {
      int j = t * 64 + lane;
      ull kw = __shfl(keep_na, t);
      if (j < TOPK) {
        bool kp = (kw >> lane) & 1ull;
        outS[(size_t)b * TOPK + j] = kp ? tS[j] : 0.f;
        outL[(size_t)b * TOPK + j] = kp ? (float)tL[j] : 0.f;
        outK[(size_t)b * TOPK + j] = kp ? 1.f : 0.f;
      }
    }
  }
}

// -------------------------------------------------------------------- host --
extern "C" void kernel_launch(void* const* d_in, const int* in_sizes, int n_in,
                              void* d_out, int out_size, void* d_ws, size_t ws_size,
                              hipStream_t stream) {
  Ptrs p;
  for (int l = 0; l < 5; ++l) {
    p.cls[l] = (const float*)d_in[l];
    p.reg[l] = (const float*)d_in[5 + l];
    p.ctr[l] = (const float*)d_in[10 + l];
  }
  char* ws = (char*)d_ws;
  size_t o = 0;
  auto alloc = [&](size_t bytes) -> void* {
    void* r = ws + o; o += (bytes + 255) & ~(size_t)255; return r;
  };
  ull*   keys       = (ull*)  alloc((size_t)BATCH * NPAD * 8);
  int*   labels     = (int*)  alloc((size_t)BATCH * NLOC * 4);
  float* boxes      = (float*)alloc((size_t)BATCH * NLOC * 16);
  ull*   runs       = (ull*)  alloc((size_t)BATCH * NCHUNK * TOPKP * 8);
  float* topS       = (float*)alloc((size_t)BATCH * TOPKP * 4);
  int*   topL       = (int*)  alloc((size_t)BATCH * TOPKP * 4);
  float* topOB      = (float*)alloc((size_t)BATCH * TOPKP * 16);
  ull*   validWords = (ull*)  alloc((size_t)BATCH * 16 * 8);
  ull*   sup        = (ull*)  alloc((size_t)BATCH * TOPKP * 16 * 8);

  float* out = (float*)d_out;
  float* outBoxes = out + 2 * BATCH * TOPK;   // offset 32000

  hipLaunchKernelGGL(score_kernel, dim3((BATCH * NPAD + 255) / 256), dim3(256), 0, stream,
                     p, keys, labels, boxes);
  hipLaunchKernelGGL(chunk_sort_kernel, dim3(BATCH * NCHUNK), dim3(512), 0, stream,
                     keys, runs);
  hipLaunchKernelGGL(merge_gather_kernel, dim3(BATCH), dim3(512), 0, stream,
                     runs, labels, boxes, topS, topL, topOB, validWords, outBoxes);
  hipLaunchKernelGGL(sup_kernel, dim3(BATCH * TOPK), dim3(1024), 0, stream,
                     topOB, sup);
  hipLaunchKernelGGL(nms_scan_kernel, dim3(BATCH), dim3(256), 0, stream,
                     sup, validWords, topS, topL, out);
}